// Round 4
// baseline (38.503 us; speedup 1.0000x reference)
//
#include <hip/hip_runtime.h>
#include <hip/hip_bf16.h>

// per-sample L1 loss (mean over D=16), weighted by (1 + 0.1*x[:,3]), mean
// over B. Two-stage reduce (R2: removed same-line atomics, -32us, confirmed).
// R3: 2 rows per thread (t and t+B/2, both streams stay perfectly coalesced),
// 512-thread blocks, grid 3907->977. Tests the latency hypothesis: doubles
// bytes-in-flight per wave, 4x fewer workgroups, 4x fewer stage2 partials.

__global__ __launch_bounds__(512)
void weighted_l1_stage1(const float4* __restrict__ outp,
                        const float4* __restrict__ tgtp,
                        const float* __restrict__ x,
                        float* __restrict__ partial,
                        int B, int half, float inv_scale) {
    int t = blockIdx.x * blockDim.x + threadIdx.x;
    float acc = 0.0f;

    if (t < half) {
        int i1 = t;
        int i2 = t + half;
        const float4* oA = outp + (size_t)i1 * 4;
        const float4* tA = tgtp + (size_t)i1 * 4;
        const float4* oB = outp + (size_t)i2 * 4;
        const float4* tB = tgtp + (size_t)i2 * 4;
        // 18 independent loads issued up front
        float4 a0 = oA[0], a1 = oA[1], a2 = oA[2], a3 = oA[3];
        float4 b0 = tA[0], b1 = tA[1], b2 = tA[2], b3 = tA[3];
        float4 c0 = oB[0], c1 = oB[1], c2 = oB[2], c3 = oB[3];
        float4 d0 = tB[0], d1 = tB[1], d2 = tB[2], d3 = tB[3];
        float x1 = x[(size_t)i1 * 8 + 3];
        float x2 = x[(size_t)i2 * 8 + 3];

        float s1 = fabsf(a0.x - b0.x) + fabsf(a0.y - b0.y)
                 + fabsf(a0.z - b0.z) + fabsf(a0.w - b0.w)
                 + fabsf(a1.x - b1.x) + fabsf(a1.y - b1.y)
                 + fabsf(a1.z - b1.z) + fabsf(a1.w - b1.w)
                 + fabsf(a2.x - b2.x) + fabsf(a2.y - b2.y)
                 + fabsf(a2.z - b2.z) + fabsf(a2.w - b2.w)
                 + fabsf(a3.x - b3.x) + fabsf(a3.y - b3.y)
                 + fabsf(a3.z - b3.z) + fabsf(a3.w - b3.w);
        float s2 = fabsf(c0.x - d0.x) + fabsf(c0.y - d0.y)
                 + fabsf(c0.z - d0.z) + fabsf(c0.w - d0.w)
                 + fabsf(c1.x - d1.x) + fabsf(c1.y - d1.y)
                 + fabsf(c1.z - d1.z) + fabsf(c1.w - d1.w)
                 + fabsf(c2.x - d2.x) + fabsf(c2.y - d2.y)
                 + fabsf(c2.z - d2.z) + fabsf(c2.w - d2.w)
                 + fabsf(c3.x - d3.x) + fabsf(c3.y - d3.y)
                 + fabsf(c3.z - d3.z) + fabsf(c3.w - d3.w);
        acc = (s1 * fmaf(0.1f, x1, 1.0f) + s2 * fmaf(0.1f, x2, 1.0f)) * inv_scale;
    }
    // odd-B tail row (B even in practice; keep correct anyway)
    if ((half * 2 < B) && t == 0) {
        int i = B - 1;
        const float4* o4 = outp + (size_t)i * 4;
        const float4* t4 = tgtp + (size_t)i * 4;
        float s = 0.0f;
        #pragma unroll
        for (int q = 0; q < 4; ++q) {
            float4 a = o4[q], b = t4[q];
            s += fabsf(a.x - b.x) + fabsf(a.y - b.y)
               + fabsf(a.z - b.z) + fabsf(a.w - b.w);
        }
        acc += s * fmaf(0.1f, x[(size_t)i * 8 + 3], 1.0f) * inv_scale;
    }

    // wave-64 reduce
    #pragma unroll
    for (int off = 32; off > 0; off >>= 1)
        acc += __shfl_down(acc, off);

    __shared__ float wsum[8];  // 512 threads = 8 waves
    int lane = threadIdx.x & 63;
    int wid  = threadIdx.x >> 6;
    if (lane == 0) wsum[wid] = acc;
    __syncthreads();
    if (threadIdx.x == 0) {
        float tsum = wsum[0] + wsum[1] + wsum[2] + wsum[3]
                   + wsum[4] + wsum[5] + wsum[6] + wsum[7];
        partial[blockIdx.x] = tsum;
    }
}

__global__ void weighted_l1_stage2(const float* __restrict__ partial,
                                   float* __restrict__ res, int n) {
    float acc = 0.0f;
    for (int j = threadIdx.x; j < n; j += 256)
        acc += partial[j];

    #pragma unroll
    for (int off = 32; off > 0; off >>= 1)
        acc += __shfl_down(acc, off);

    __shared__ float wsum[4];
    int lane = threadIdx.x & 63;
    int wid  = threadIdx.x >> 6;
    if (lane == 0) wsum[wid] = acc;
    __syncthreads();
    if (threadIdx.x == 0)
        res[0] = wsum[0] + wsum[1] + wsum[2] + wsum[3];
}

extern "C" void kernel_launch(void* const* d_in, const int* in_sizes, int n_in,
                              void* d_out, int out_size, void* d_ws, size_t ws_size,
                              hipStream_t stream) {
    const float* outp = (const float*)d_in[0];  // [B,16]
    const float* tgtp = (const float*)d_in[1];  // [B,16]
    const float* x    = (const float*)d_in[2];  // [B,8]
    float* res = (float*)d_out;
    float* partial = (float*)d_ws;  // grid*4 bytes (~4 KB)

    int B = in_sizes[0] / 16;
    int half = B / 2;

    int block = 512;
    int grid  = (half + block - 1) / block;  // 977 for B=1e6
    if (grid < 1) grid = 1;

    weighted_l1_stage1<<<grid, block, 0, stream>>>(
        (const float4*)outp, (const float4*)tgtp, x, partial,
        B, half, 1.0f / (16.0f * (float)B));
    weighted_l1_stage2<<<1, 256, 0, stream>>>(partial, res, grid);
}

// Round 5
// 33.132 us; speedup vs baseline: 1.1621x; 1.1621x over previous
//
#include <hip/hip_runtime.h>
#include <hip/hip_bf16.h>

// per-sample L1 loss (mean over D=16), weighted by (1 + 0.1*x[:,3]), mean
// over B. Two-stage reduce (R2: no same-line atomics). R4: 2 CONSECUTIVE
// rows per thread -- keeps R2's single contiguous sweep (FETCH ~78 MB,
// L3-friendly; R3's split streams fetched 107 MB) while retaining R3's
// 18-deep per-thread load issue (proven +0.4 TB/s achieved HBM BW).

__global__ __launch_bounds__(256)
void weighted_l1_stage1(const float4* __restrict__ outp,
                        const float4* __restrict__ tgtp,
                        const float* __restrict__ x,
                        float* __restrict__ partial,
                        int npairs, int B, float inv_scale) {
    int t = blockIdx.x * blockDim.x + threadIdx.x;
    float acc = 0.0f;

    if (t < npairs) {
        size_t r = (size_t)t * 2;             // rows r, r+1 (consecutive)
        const float4* oA = outp + r * 4;      // 8 float4 = rows r..r+1 of out
        const float4* tA = tgtp + r * 4;
        // 18 independent loads issued before any use
        float4 a0 = oA[0], a1 = oA[1], a2 = oA[2], a3 = oA[3];
        float4 c0 = oA[4], c1 = oA[5], c2 = oA[6], c3 = oA[7];
        float4 b0 = tA[0], b1 = tA[1], b2 = tA[2], b3 = tA[3];
        float4 d0 = tA[4], d1 = tA[5], d2 = tA[6], d3 = tA[7];
        float x1 = x[r * 8 + 3];
        float x2 = x[r * 8 + 11];

        float s1 = fabsf(a0.x - b0.x) + fabsf(a0.y - b0.y)
                 + fabsf(a0.z - b0.z) + fabsf(a0.w - b0.w)
                 + fabsf(a1.x - b1.x) + fabsf(a1.y - b1.y)
                 + fabsf(a1.z - b1.z) + fabsf(a1.w - b1.w)
                 + fabsf(a2.x - b2.x) + fabsf(a2.y - b2.y)
                 + fabsf(a2.z - b2.z) + fabsf(a2.w - b2.w)
                 + fabsf(a3.x - b3.x) + fabsf(a3.y - b3.y)
                 + fabsf(a3.z - b3.z) + fabsf(a3.w - b3.w);
        float s2 = fabsf(c0.x - d0.x) + fabsf(c0.y - d0.y)
                 + fabsf(c0.z - d0.z) + fabsf(c0.w - d0.w)
                 + fabsf(c1.x - d1.x) + fabsf(c1.y - d1.y)
                 + fabsf(c1.z - d1.z) + fabsf(c1.w - d1.w)
                 + fabsf(c2.x - d2.x) + fabsf(c2.y - d2.y)
                 + fabsf(c2.z - d2.z) + fabsf(c2.w - d2.w)
                 + fabsf(c3.x - d3.x) + fabsf(c3.y - d3.y)
                 + fabsf(c3.z - d3.z) + fabsf(c3.w - d3.w);
        acc = (s1 * fmaf(0.1f, x1, 1.0f) + s2 * fmaf(0.1f, x2, 1.0f)) * inv_scale;
    }
    // odd-B tail row (B=1e6 is even; kept for generality)
    if ((npairs * 2 < B) && t == 0) {
        size_t i = (size_t)B - 1;
        const float4* o4 = outp + i * 4;
        const float4* t4 = tgtp + i * 4;
        float s = 0.0f;
        #pragma unroll
        for (int q = 0; q < 4; ++q) {
            float4 a = o4[q], b = t4[q];
            s += fabsf(a.x - b.x) + fabsf(a.y - b.y)
               + fabsf(a.z - b.z) + fabsf(a.w - b.w);
        }
        acc += s * fmaf(0.1f, x[i * 8 + 3], 1.0f) * inv_scale;
    }

    // wave-64 reduce
    #pragma unroll
    for (int off = 32; off > 0; off >>= 1)
        acc += __shfl_down(acc, off);

    __shared__ float wsum[4];  // 256 threads = 4 waves
    int lane = threadIdx.x & 63;
    int wid  = threadIdx.x >> 6;
    if (lane == 0) wsum[wid] = acc;
    __syncthreads();
    if (threadIdx.x == 0)
        partial[blockIdx.x] = wsum[0] + wsum[1] + wsum[2] + wsum[3];
}

__global__ void weighted_l1_stage2(const float* __restrict__ partial,
                                   float* __restrict__ res, int n) {
    float acc = 0.0f;
    for (int j = threadIdx.x; j < n; j += 256)
        acc += partial[j];

    #pragma unroll
    for (int off = 32; off > 0; off >>= 1)
        acc += __shfl_down(acc, off);

    __shared__ float wsum[4];
    int lane = threadIdx.x & 63;
    int wid  = threadIdx.x >> 6;
    if (lane == 0) wsum[wid] = acc;
    __syncthreads();
    if (threadIdx.x == 0)
        res[0] = wsum[0] + wsum[1] + wsum[2] + wsum[3];
}

extern "C" void kernel_launch(void* const* d_in, const int* in_sizes, int n_in,
                              void* d_out, int out_size, void* d_ws, size_t ws_size,
                              hipStream_t stream) {
    const float* outp = (const float*)d_in[0];  // [B,16]
    const float* tgtp = (const float*)d_in[1];  // [B,16]
    const float* x    = (const float*)d_in[2];  // [B,8]
    float* res = (float*)d_out;
    float* partial = (float*)d_ws;  // grid*4 bytes (~8 KB)

    int B = in_sizes[0] / 16;
    int npairs = B / 2;

    int block = 256;
    int grid  = (npairs + block - 1) / block;  // 1954 for B=1e6
    if (grid < 1) grid = 1;

    weighted_l1_stage1<<<grid, block, 0, stream>>>(
        (const float4*)outp, (const float4*)tgtp, x, partial,
        npairs, B, 1.0f / (16.0f * (float)B));
    weighted_l1_stage2<<<1, 256, 0, stream>>>(partial, res, grid);
}

// Round 6
// 30.930 us; speedup vs baseline: 1.2448x; 1.0712x over previous
//
#include <hip/hip_runtime.h>
#include <hip/hip_bf16.h>

// per-sample L1 loss (mean over D=16), weighted by (1 + 0.1*x[:,3]), mean
// over B. Two-stage reduce (R2: no same-line atomics -32us).
// R5: flat float4 indexing (lane stride 16B -> each wave load = 1KB
// contiguous, 8 cache lines, no request amplification; R2/R4's row-per-
// thread layouts had 64B/128B lane strides = 4-8x line-requests per
// instruction) PLUS deep MLP (8 chunks/thread spaced by blockDim, 24
// independent loads issued up front). R0 proved coalescing alone isn't
// enough (shallow MLP); R4 proved MLP alone isn't enough (amplification).

__global__ __launch_bounds__(256)
void weighted_l1_stage1(const float4* __restrict__ outp,
                        const float4* __restrict__ tgtp,
                        const float* __restrict__ x,
                        float* __restrict__ partial,
                        size_t n4, float inv_scale) {
    const int ITER = 8;
    size_t base = (size_t)blockIdx.x * (256 * ITER) + threadIdx.x;
    float acc = 0.0f;

    if ((size_t)(blockIdx.x + 1) * (256 * ITER) <= n4) {
        // full block: 16 float4 + 8 scalar loads, all issued before use,
        // every instruction perfectly coalesced (16B lane stride)
        float4 a0 = outp[base + 0 * 256], a1 = outp[base + 1 * 256],
               a2 = outp[base + 2 * 256], a3 = outp[base + 3 * 256],
               a4 = outp[base + 4 * 256], a5 = outp[base + 5 * 256],
               a6 = outp[base + 6 * 256], a7 = outp[base + 7 * 256];
        float4 b0 = tgtp[base + 0 * 256], b1 = tgtp[base + 1 * 256],
               b2 = tgtp[base + 2 * 256], b3 = tgtp[base + 3 * 256],
               b4 = tgtp[base + 4 * 256], b5 = tgtp[base + 5 * 256],
               b6 = tgtp[base + 6 * 256], b7 = tgtp[base + 7 * 256];
        float w0 = x[((base + 0 * 256) >> 2) * 8 + 3],
              w1 = x[((base + 1 * 256) >> 2) * 8 + 3],
              w2 = x[((base + 2 * 256) >> 2) * 8 + 3],
              w3 = x[((base + 3 * 256) >> 2) * 8 + 3],
              w4 = x[((base + 4 * 256) >> 2) * 8 + 3],
              w5 = x[((base + 5 * 256) >> 2) * 8 + 3],
              w6 = x[((base + 6 * 256) >> 2) * 8 + 3],
              w7 = x[((base + 7 * 256) >> 2) * 8 + 3];

        float s0 = fabsf(a0.x-b0.x)+fabsf(a0.y-b0.y)+fabsf(a0.z-b0.z)+fabsf(a0.w-b0.w);
        float s1 = fabsf(a1.x-b1.x)+fabsf(a1.y-b1.y)+fabsf(a1.z-b1.z)+fabsf(a1.w-b1.w);
        float s2 = fabsf(a2.x-b2.x)+fabsf(a2.y-b2.y)+fabsf(a2.z-b2.z)+fabsf(a2.w-b2.w);
        float s3 = fabsf(a3.x-b3.x)+fabsf(a3.y-b3.y)+fabsf(a3.z-b3.z)+fabsf(a3.w-b3.w);
        float s4 = fabsf(a4.x-b4.x)+fabsf(a4.y-b4.y)+fabsf(a4.z-b4.z)+fabsf(a4.w-b4.w);
        float s5 = fabsf(a5.x-b5.x)+fabsf(a5.y-b5.y)+fabsf(a5.z-b5.z)+fabsf(a5.w-b5.w);
        float s6 = fabsf(a6.x-b6.x)+fabsf(a6.y-b6.y)+fabsf(a6.z-b6.z)+fabsf(a6.w-b6.w);
        float s7 = fabsf(a7.x-b7.x)+fabsf(a7.y-b7.y)+fabsf(a7.z-b7.z)+fabsf(a7.w-b7.w);

        acc = s0 * fmaf(0.1f, w0, 1.0f) + s1 * fmaf(0.1f, w1, 1.0f)
            + s2 * fmaf(0.1f, w2, 1.0f) + s3 * fmaf(0.1f, w3, 1.0f)
            + s4 * fmaf(0.1f, w4, 1.0f) + s5 * fmaf(0.1f, w5, 1.0f)
            + s6 * fmaf(0.1f, w6, 1.0f) + s7 * fmaf(0.1f, w7, 1.0f);
        acc *= inv_scale;
    } else {
        // tail block: guarded per-chunk
        for (int k = 0; k < ITER; ++k) {
            size_t c = base + (size_t)k * 256;
            if (c < n4) {
                float4 a = outp[c], b = tgtp[c];
                float s = fabsf(a.x-b.x)+fabsf(a.y-b.y)+fabsf(a.z-b.z)+fabsf(a.w-b.w);
                float w = fmaf(0.1f, x[(c >> 2) * 8 + 3], 1.0f);
                acc += s * w * inv_scale;
            }
        }
    }

    // wave-64 reduce
    #pragma unroll
    for (int off = 32; off > 0; off >>= 1)
        acc += __shfl_down(acc, off);

    __shared__ float wsum[4];  // 256 threads = 4 waves
    int lane = threadIdx.x & 63;
    int wid  = threadIdx.x >> 6;
    if (lane == 0) wsum[wid] = acc;
    __syncthreads();
    if (threadIdx.x == 0)
        partial[blockIdx.x] = wsum[0] + wsum[1] + wsum[2] + wsum[3];
}

__global__ void weighted_l1_stage2(const float* __restrict__ partial,
                                   float* __restrict__ res, int n) {
    float acc = 0.0f;
    for (int j = threadIdx.x; j < n; j += 256)
        acc += partial[j];

    #pragma unroll
    for (int off = 32; off > 0; off >>= 1)
        acc += __shfl_down(acc, off);

    __shared__ float wsum[4];
    int lane = threadIdx.x & 63;
    int wid  = threadIdx.x >> 6;
    if (lane == 0) wsum[wid] = acc;
    __syncthreads();
    if (threadIdx.x == 0)
        res[0] = wsum[0] + wsum[1] + wsum[2] + wsum[3];
}

extern "C" void kernel_launch(void* const* d_in, const int* in_sizes, int n_in,
                              void* d_out, int out_size, void* d_ws, size_t ws_size,
                              hipStream_t stream) {
    const float* outp = (const float*)d_in[0];  // [B,16]
    const float* tgtp = (const float*)d_in[1];  // [B,16]
    const float* x    = (const float*)d_in[2];  // [B,8]
    float* res = (float*)d_out;
    float* partial = (float*)d_ws;  // grid*4 bytes (~8 KB)

    int B = in_sizes[0] / 16;
    size_t n4 = (size_t)B * 4;  // total float4 chunks

    int block = 256;
    int chunks_per_block = block * 8;
    int grid = (int)((n4 + chunks_per_block - 1) / chunks_per_block);  // 1954
    if (grid < 1) grid = 1;

    weighted_l1_stage1<<<grid, block, 0, stream>>>(
        (const float4*)outp, (const float4*)tgtp, x, partial,
        n4, 1.0f / (16.0f * (float)B));
    weighted_l1_stage2<<<1, 256, 0, stream>>>(partial, res, grid);
}

// Round 7
// 30.309 us; speedup vs baseline: 1.2704x; 1.0205x over previous
//
#include <hip/hip_runtime.h>
#include <hip/hip_bf16.h>

// per-sample L1 loss (mean over D=16), weighted by (1 + 0.1*x[:,3]), mean
// over B. Two-stage reduce (R2). Flat float4 indexing, 16B lane stride
// (R5: every wave load = 1KB contiguous). R6: FORCED deep issue -- R5's
// rocprof showed VGPR=32, i.e. the compiler recycled dest regs and kept
// only ~6-8 loads in flight despite source-level 24-deep issue. An
// asm memory-clobber between the loads and their consumption pins all 24
// loads before any use (loads can't sink past the clobber), holding ~72
// dest VGPRs live. Decisive test: MLP-limited vs service-rate-limited.

__global__ __launch_bounds__(256)
void weighted_l1_stage1(const float4* __restrict__ outp,
                        const float4* __restrict__ tgtp,
                        const float* __restrict__ x,
                        float* __restrict__ partial,
                        size_t n4, float inv_scale) {
    const int ITER = 8;
    size_t base = (size_t)blockIdx.x * (256 * ITER) + threadIdx.x;
    float acc = 0.0f;

    if ((size_t)(blockIdx.x + 1) * (256 * ITER) <= n4) {
        float4 a[ITER], b[ITER];
        float  w[ITER];
        #pragma unroll
        for (int k = 0; k < ITER; ++k) a[k] = outp[base + (size_t)k * 256];
        #pragma unroll
        for (int k = 0; k < ITER; ++k) b[k] = tgtp[base + (size_t)k * 256];
        #pragma unroll
        for (int k = 0; k < ITER; ++k)
            w[k] = x[((base + (size_t)k * 256) >> 2) * 8 + 3];

        // pin: all 24 loads issued before any consumption can retire regs
        asm volatile("" ::: "memory");

        #pragma unroll
        for (int k = 0; k < ITER; ++k) {
            float s = fabsf(a[k].x - b[k].x) + fabsf(a[k].y - b[k].y)
                    + fabsf(a[k].z - b[k].z) + fabsf(a[k].w - b[k].w);
            acc += s * fmaf(0.1f, w[k], 1.0f);
        }
        acc *= inv_scale;
    } else {
        for (int k = 0; k < ITER; ++k) {
            size_t c = base + (size_t)k * 256;
            if (c < n4) {
                float4 a = outp[c], b = tgtp[c];
                float s = fabsf(a.x-b.x)+fabsf(a.y-b.y)+fabsf(a.z-b.z)+fabsf(a.w-b.w);
                float w = fmaf(0.1f, x[(c >> 2) * 8 + 3], 1.0f);
                acc += s * w * inv_scale;
            }
        }
    }

    // wave-64 reduce
    #pragma unroll
    for (int off = 32; off > 0; off >>= 1)
        acc += __shfl_down(acc, off);

    __shared__ float wsum[4];
    int lane = threadIdx.x & 63;
    int wid  = threadIdx.x >> 6;
    if (lane == 0) wsum[wid] = acc;
    __syncthreads();
    if (threadIdx.x == 0)
        partial[blockIdx.x] = wsum[0] + wsum[1] + wsum[2] + wsum[3];
}

__global__ void weighted_l1_stage2(const float* __restrict__ partial,
                                   float* __restrict__ res, int n) {
    // vectorized: n partials as float4 groups + scalar tail
    int n4 = n >> 2;
    const float4* p4 = (const float4*)partial;
    float acc = 0.0f;
    for (int j = threadIdx.x; j < n4; j += 256) {
        float4 v = p4[j];
        acc += v.x + v.y + v.z + v.w;
    }
    for (int j = (n4 << 2) + threadIdx.x; j < n; j += 256)
        acc += partial[j];

    #pragma unroll
    for (int off = 32; off > 0; off >>= 1)
        acc += __shfl_down(acc, off);

    __shared__ float wsum[4];
    int lane = threadIdx.x & 63;
    int wid  = threadIdx.x >> 6;
    if (lane == 0) wsum[wid] = acc;
    __syncthreads();
    if (threadIdx.x == 0)
        res[0] = wsum[0] + wsum[1] + wsum[2] + wsum[3];
}

extern "C" void kernel_launch(void* const* d_in, const int* in_sizes, int n_in,
                              void* d_out, int out_size, void* d_ws, size_t ws_size,
                              hipStream_t stream) {
    const float* outp = (const float*)d_in[0];  // [B,16]
    const float* tgtp = (const float*)d_in[1];  // [B,16]
    const float* x    = (const float*)d_in[2];  // [B,8]
    float* res = (float*)d_out;
    float* partial = (float*)d_ws;  // grid*4 bytes (~8 KB)

    int B = in_sizes[0] / 16;
    size_t n4 = (size_t)B * 4;

    int block = 256;
    int chunks_per_block = block * 8;
    int grid = (int)((n4 + chunks_per_block - 1) / chunks_per_block);  // 1954
    if (grid < 1) grid = 1;

    weighted_l1_stage1<<<grid, block, 0, stream>>>(
        (const float4*)outp, (const float4*)tgtp, x, partial,
        n4, 1.0f / (16.0f * (float)B));
    weighted_l1_stage2<<<1, 256, 0, stream>>>(partial, res, grid);
}